// Round 3
// baseline (123.964 us; speedup 1.0000x reference)
//
#include <hip/hip_runtime.h>

#define BATCH 131072
#define SC 2.885390081777927f   // 2*log2(e), folded into W1',b1',W2',b2'

typedef _Float16 half4 __attribute__((ext_vector_type(4)));
typedef float floatx4 __attribute__((ext_vector_type(4)));

__device__ __forceinline__ half4 u2h(uint2 u) { return __builtin_bit_cast(half4, u); }

// ws layout (_Float16 elements):
// [0,18432)      W2a: A-frag pairs of W2'^T incl bias row. idx=((ntp*9+kb)*64+lane)*8+half*4+j
//                A[m=(2ntp+half)*16+(lane&15)][k=kb*16+(lane>>4)*4+j] = SC*W2[k][m] (k=128 -> SC*b2[m])
// [18432,34816)  Ga : A-frag pairs of G, G[h][g]=W2[h][g]*C[g][h], C=W3@W1[:8,:]
//                idx=18432+((ntp*8+kb)*64+lane)*8+half*4+j ; m=h, k=g
// [34816,36864)  W1a: A-frags of W1'^T (K=16: 9 real + bias row k=9). idx=34816+(nt*64+lane)*4+j
// [36864,39168)  W3a: A-frags of W3^T (N pad 16, K=144 incl bias row). idx=36864+(kb*64+lane)*4+j

__global__ void prep_kernel(const float* __restrict__ W1, const float* __restrict__ b1,
                            const float* __restrict__ W2, const float* __restrict__ b2,
                            const float* __restrict__ W3, const float* __restrict__ b3,
                            _Float16* __restrict__ ws) {
    int idx = blockIdx.x * 256 + threadIdx.x;
    if (idx < 18432) {
        int j = idx & 3, hf = (idx >> 2) & 1, lane = (idx >> 3) & 63;
        int rem = idx >> 9, kb = rem % 9, ntp = rem / 9;
        int m = (2 * ntp + hf) * 16 + (lane & 15);
        int k = kb * 16 + (lane >> 4) * 4 + j;
        float v = (k < 128) ? SC * W2[k * 128 + m] : ((k == 128) ? SC * b2[m] : 0.0f);
        ws[idx] = (_Float16)v;
    } else if (idx < 34816) {
        int e = idx - 18432;
        int j = e & 3, hf = (e >> 2) & 1, lane = (e >> 3) & 63;
        int rem = e >> 9, kb = rem & 7, ntp = rem >> 3;
        int h = (2 * ntp + hf) * 16 + (lane & 15);
        int g = kb * 16 + (lane >> 4) * 4 + j;
        float c = 0.0f;
        #pragma unroll
        for (int d = 0; d < 8; ++d) c += W3[g * 8 + d] * W1[d * 128 + h];
        ws[idx] = (_Float16)(W2[h * 128 + g] * c);
    } else if (idx < 36864) {
        int e = idx - 34816;
        int j = e & 3, lane = (e >> 2) & 63, nt = e >> 8;
        int h = nt * 16 + (lane & 15);
        int k = (lane >> 4) * 4 + j;
        float v = (k < 9) ? SC * W1[k * 128 + h] : ((k == 9) ? SC * b1[h] : 0.0f);
        ws[idx] = (_Float16)v;
    } else if (idx < 39168) {
        int e = idx - 36864;
        int j = e & 3, lane = (e >> 2) & 63, kb = e >> 8;
        int m = lane & 15, k = kb * 16 + (lane >> 4) * 4 + j;
        float v = 0.0f;
        if (m < 8) v = (k < 128) ? W3[k * 8 + m] : ((k == 128) ? b3[m] : 0.0f);
        ws[idx] = (_Float16)v;
    }
}

__global__ __launch_bounds__(256, 4) void cnf_main(
        const float* __restrict__ z, const float* __restrict__ t_ptr,
        const _Float16* __restrict__ ws, float* __restrict__ out) {
    __shared__ unsigned short sW2[18432];   // 36,864 B: W2a A-frag pairs

    const int tid = threadIdx.x;
    {   // stage W2a: 2304 uint4
        const uint4* src = (const uint4*)ws;
        uint4* dst = (uint4*)sW2;
        #pragma unroll
        for (int i = 0; i < 9; ++i) dst[tid + i * 256] = src[tid + i * 256];
    }
    __syncthreads();

    const int lane = tid & 63;
    const int w = tid >> 6;
    const int p = lane & 15;     // sample within tile (B col / CD col)
    const int q = lane >> 4;     // quad

    // register-resident weight fragments
    half4 W1f[8], W3f[9];
    {
        const uint2* w1a = (const uint2*)(ws + 34816);
        #pragma unroll
        for (int nt = 0; nt < 8; ++nt) W1f[nt] = u2h(w1a[nt * 64 + lane]);
        const uint2* w3a = (const uint2*)(ws + 36864);
        #pragma unroll
        for (int kb = 0; kb < 9; ++kb) W3f[kb] = u2h(w3a[kb * 64 + lane]);
    }
    half4 e1 = {(_Float16)0.0f, (_Float16)0.0f, (_Float16)0.0f, (_Float16)0.0f};
    if (q == 0) e1[0] = (_Float16)1.0f;
    const float tval = t_ptr[0];
    const uint4* sW2v = (const uint4*)sW2;
    const uint4* gav = (const uint4*)(ws + 18432);

    #pragma unroll
    for (int it = 0; it < 2; ++it) {
        const int s0 = blockIdx.x * 128 + w * 32 + it * 16;

        // ---- B-frag of X^T: B[k][n=sample]; k=q*4+j; rows 0-7=z, 8=t, 9=1(bias), rest 0
        const float4 zv = *(const float4*)(z + (size_t)(s0 + p) * 8 + (q & 1) * 4);
        half4 xb;
        if (q < 2) {
            xb[0] = (_Float16)zv.x; xb[1] = (_Float16)zv.y;
            xb[2] = (_Float16)zv.z; xb[3] = (_Float16)zv.w;
        } else if (q == 2) {
            xb[0] = (_Float16)tval; xb[1] = (_Float16)1.0f;
            xb[2] = (_Float16)0.0f; xb[3] = (_Float16)0.0f;
        } else {
            xb[0] = (_Float16)0.0f; xb[1] = (_Float16)0.0f;
            xb[2] = (_Float16)0.0f; xb[3] = (_Float16)0.0f;
        }

        // ---- GEMM0: H1^T = W1'^T @ X^T (bias+scale folded); tanh; keep h1,a1 frags
        half4 h1f[8], a1f[8];
        #pragma unroll
        for (int nt = 0; nt < 8; ++nt) {
            floatx4 a0 = {0.f, 0.f, 0.f, 0.f};
            a0 = __builtin_amdgcn_mfma_f32_16x16x16f16(W1f[nt], xb, a0, 0, 0, 0);
            #pragma unroll
            for (int r = 0; r < 4; ++r) {
                const float e = __builtin_amdgcn_exp2f(a0[r]);
                const float rr = __builtin_amdgcn_rcpf(e + 1.0f);
                const float h = __builtin_fmaf(-2.0f, rr, 1.0f);
                h1f[nt][r] = (_Float16)h;
                a1f[nt][r] = (_Float16)__builtin_fmaf(-h, h, 1.0f);
            }
        }

        // ---- GEMM1: H2pre^T = W2'^T @ H1^T (+bias row): C/D of GEMM0 IS the B-frag
        floatx4 acc[8];
        #pragma unroll
        for (int nt = 0; nt < 8; ++nt) acc[nt] = (floatx4){0.f, 0.f, 0.f, 0.f};
        #pragma unroll
        for (int kb = 0; kb < 9; ++kb) {
            const half4 bfrag = (kb < 8) ? h1f[kb] : e1;
            #pragma unroll
            for (int ntp = 0; ntp < 4; ++ntp) {
                const uint4 af = sW2v[(ntp * 9 + kb) * 64 + lane];
                acc[2 * ntp] = __builtin_amdgcn_mfma_f32_16x16x16f16(
                        u2h((uint2){af.x, af.y}), bfrag, acc[2 * ntp], 0, 0, 0);
                acc[2 * ntp + 1] = __builtin_amdgcn_mfma_f32_16x16x16f16(
                        u2h((uint2){af.z, af.w}), bfrag, acc[2 * ntp + 1], 0, 0, 0);
            }
        }

        // ---- tanh -> h2, a2 frags (again: C/D layout == next B-frag layout)
        half4 h2f[8], a2f[8];
        #pragma unroll
        for (int nt = 0; nt < 8; ++nt) {
            #pragma unroll
            for (int r = 0; r < 4; ++r) {
                const float e = __builtin_amdgcn_exp2f(acc[nt][r]);
                const float rr = __builtin_amdgcn_rcpf(e + 1.0f);
                const float h = __builtin_fmaf(-2.0f, rr, 1.0f);
                h2f[nt][r] = (_Float16)h;
                a2f[nt][r] = (_Float16)__builtin_fmaf(-h, h, 1.0f);
            }
        }

        // ---- GEMM3: dz^T = W3^T @ H2^T (+bias row); rows = output dim d
        floatx4 acc3 = {0.f, 0.f, 0.f, 0.f};
        #pragma unroll
        for (int kb = 0; kb < 9; ++kb)
            acc3 = __builtin_amdgcn_mfma_f32_16x16x16f16(
                    W3f[kb], (kb < 8) ? h2f[kb] : e1, acc3, 0, 0, 0);
        if (q < 2) {   // d = q*4+r in [0,8): one float4 store per lane, contiguous
            float4 o; o.x = acc3[0]; o.y = acc3[1]; o.z = acc3[2]; o.w = acc3[3];
            *(float4*)(out + (size_t)(s0 + p) * 8 + q * 4) = o;
        }

        // ---- GEMM2: U^T = G @ A2^T  (G A-frags streamed from global, L1-hot)
        floatx4 accU[8];
        #pragma unroll
        for (int nt = 0; nt < 8; ++nt) accU[nt] = (floatx4){0.f, 0.f, 0.f, 0.f};
        #pragma unroll
        for (int kb = 0; kb < 8; ++kb) {
            #pragma unroll
            for (int ntp = 0; ntp < 4; ++ntp) {
                const uint4 gf = gav[(ntp * 8 + kb) * 64 + lane];
                accU[2 * ntp] = __builtin_amdgcn_mfma_f32_16x16x16f16(
                        u2h((uint2){gf.x, gf.y}), a2f[kb], accU[2 * ntp], 0, 0, 0);
                accU[2 * ntp + 1] = __builtin_amdgcn_mfma_f32_16x16x16f16(
                        u2h((uint2){gf.z, gf.w}), a2f[kb], accU[2 * ntp + 1], 0, 0, 0);
            }
        }

        // ---- trace: a1 and U share (lane,reg) mapping -> register dot, then 2 shuffles
        float tr = 0.0f;
        #pragma unroll
        for (int nt = 0; nt < 8; ++nt) {
            #pragma unroll
            for (int r = 0; r < 4; ++r)
                tr = __builtin_fmaf((float)a1f[nt][r], accU[nt][r], tr);
        }
        tr += __shfl_xor(tr, 16, 64);
        tr += __shfl_xor(tr, 32, 64);
        if (q == 0) out[(size_t)BATCH * 8 + s0 + p] = -tr;
    }
}

extern "C" void kernel_launch(void* const* d_in, const int* in_sizes, int n_in,
                              void* d_out, int out_size, void* d_ws, size_t ws_size,
                              hipStream_t stream) {
    const float* z  = (const float*)d_in[0];
    // d_in[1] = logp_z (unused by the reference math)
    const float* t  = (const float*)d_in[2];
    const float* W1 = (const float*)d_in[3];
    const float* b1 = (const float*)d_in[4];
    const float* W2 = (const float*)d_in[5];
    const float* b2 = (const float*)d_in[6];
    const float* W3 = (const float*)d_in[7];
    const float* b3 = (const float*)d_in[8];
    _Float16* ws = (_Float16*)d_ws;
    float* out = (float*)d_out;

    prep_kernel<<<153, 256, 0, stream>>>(W1, b1, W2, b2, W3, b3, ws);
    cnf_main<<<1024, 256, 0, stream>>>(z, t, ws, out);
}